// Round 1
// 405.007 us; speedup vs baseline: 1.0926x; 1.0926x over previous
//
#include <hip/hip_runtime.h>
#include <hip/hip_bf16.h>

#define N_NODES 8192
#define F_INDIM 512
#define H1DIM   256
#define H2DIM   64

typedef __bf16 bf16x8 __attribute__((ext_vector_type(8)));
typedef __bf16 bf16x4 __attribute__((ext_vector_type(4)));
typedef __bf16 bf16x2 __attribute__((ext_vector_type(2)));
typedef float  floatx4 __attribute__((ext_vector_type(4)));

// ---------------- CSR build ----------------
__global__ void count_rows(const int* __restrict__ rows, int* __restrict__ cnt, int e) {
    int i = blockIdx.x * blockDim.x + threadIdx.x;
    if (i < e) atomicAdd(&cnt[rows[i]], 1);
}

__global__ void scan_rows(const int* __restrict__ cnt, int* __restrict__ row_ptr,
                          int* __restrict__ cursor, int n) {
    __shared__ int sums[1024];
    int t = threadIdx.x;
    int base = t * 8;
    int loc[8];
    int s = 0;
#pragma unroll
    for (int i = 0; i < 8; ++i) { loc[i] = cnt[base + i]; s += loc[i]; }
    sums[t] = s;
    __syncthreads();
    for (int off = 1; off < 1024; off <<= 1) {
        int v = (t >= off) ? sums[t - off] : 0;
        __syncthreads();
        sums[t] += v;
        __syncthreads();
    }
    int run = sums[t] - s;
#pragma unroll
    for (int i = 0; i < 8; ++i) {
        row_ptr[base + i] = run;
        cursor[base + i]  = run;
        run += loc[i];
    }
    if (t == 1023) row_ptr[n] = run;
}

__global__ void scatter_edges(const int* __restrict__ rows, const int* __restrict__ cols,
                              const float* __restrict__ vals, int* __restrict__ cursor,
                              int* __restrict__ csr_col, float* __restrict__ csr_val, int e) {
    int i = blockIdx.x * blockDim.x + threadIdx.x;
    if (i < e) {
        int r = rows[i];
        int slot = atomicAdd(&cursor[r], 1);
        csr_col[slot] = cols[i];
        csr_val[slot] = vals[i];
    }
}

// ---------------- split casts: f32 -> bf16 hi + bf16 residual ----------------
// x[8192,512] -> xh, xl (row-major, same layout)
__global__ __launch_bounds__(256) void cast_split_x(const float* __restrict__ x,
                                                    __bf16* __restrict__ xh,
                                                    __bf16* __restrict__ xl) {
    int i = (blockIdx.x * 256 + threadIdx.x) * 4;
    floatx4 v = *(const floatx4*)&x[i];
    bf16x4 h, l;
#pragma unroll
    for (int j = 0; j < 4; ++j) {
        __bf16 hv = (__bf16)v[j];
        h[j] = hv;
        l[j] = (__bf16)(v[j] - (float)hv);
    }
    *(bf16x4*)&xh[i] = h;
    *(bf16x4*)&xl[i] = l;
}

// transpose+split: W[K,N] f32 -> out[N,K] bf16 hi/lo (w23t stacks W2 rows 0-63, W3 rows 64-127)
__global__ void transpose_cast_w(const float* __restrict__ W1, const float* __restrict__ W2,
                                 const float* __restrict__ W3,
                                 __bf16* __restrict__ w1th, __bf16* __restrict__ w1tl,
                                 __bf16* __restrict__ w23th, __bf16* __restrict__ w23tl) {
    const int z = blockIdx.z;
    const float* src; __bf16 *oh, *ol; int K, N, rowoff, outld;
    if (z == 0)      { src = W1; K = 512; N = 256; oh = w1th;  ol = w1tl;  rowoff = 0;  outld = 512; }
    else if (z == 1) { src = W2; K = 256; N = 64;  oh = w23th; ol = w23tl; rowoff = 0;  outld = 256; }
    else             { src = W3; K = 256; N = 64;  oh = w23th; ol = w23tl; rowoff = 64; outld = 256; }
    const int kt = blockIdx.x, nt = blockIdx.y;
    if (kt * 32 >= K || nt * 32 >= N) return;
    __shared__ float tile[32][33];
    const int tx = threadIdx.x, ty = threadIdx.y;   // 32 x 8
#pragma unroll
    for (int j = 0; j < 4; ++j)
        tile[ty + 8 * j][tx] = src[(size_t)(kt * 32 + ty + 8 * j) * N + nt * 32 + tx];
    __syncthreads();
#pragma unroll
    for (int j = 0; j < 4; ++j) {
        int n = nt * 32 + ty + 8 * j;
        int k = kt * 32 + tx;
        float v = tile[tx][ty + 8 * j];
        __bf16 h = (__bf16)v;
        oh[(size_t)(rowoff + n) * outld + k] = h;
        ol[(size_t)(rowoff + n) * outld + k] = (__bf16)(v - (float)h);
    }
}

// ---------------- gemm1: support = x @ W1 via split-bf16 MFMA ----------------
// BM=BN=64, BK=32, 4 waves (2x2), wave tile 32x32 (2x2 frags of 16x16x32)
// 3-term split: AhBh + AhBl + AlBh accumulated in f32 (~fp32 accuracy)
__global__ __launch_bounds__(256) void gemm1_mfma(const __bf16* __restrict__ xh,
                                                  const __bf16* __restrict__ xl,
                                                  const __bf16* __restrict__ bth,
                                                  const __bf16* __restrict__ btl,
                                                  float* __restrict__ C) {
    constexpr int K = F_INDIM, NN = H1DIM, LDSW = 40;  // 40 halves = 80 B padded rows
    __shared__ __bf16 Ah[64 * LDSW], Al[64 * LDSW], Bh[64 * LDSW], Bl[64 * LDSW];
    const int tid = threadIdx.x;
    const int m0 = blockIdx.y * 64, n0 = blockIdx.x * 64;
    const int lane = tid & 63, wv = tid >> 6;
    const int wm = wv >> 1, wn = wv & 1;
    const int r16 = lane & 15, q = lane >> 4;
    const int sr = tid >> 2, sc = (tid & 3) * 8;   // stage: 64 rows x 4 chunks of 8 halves
    floatx4 acc[2][2] = {};

    for (int k0 = 0; k0 < K; k0 += 32) {
        bf16x8 va  = *(const bf16x8*)&xh [(size_t)(m0 + sr) * K + k0 + sc];
        bf16x8 vb  = *(const bf16x8*)&bth[(size_t)(n0 + sr) * K + k0 + sc];
        bf16x8 va2 = *(const bf16x8*)&xl [(size_t)(m0 + sr) * K + k0 + sc];
        bf16x8 vb2 = *(const bf16x8*)&btl[(size_t)(n0 + sr) * K + k0 + sc];
        __syncthreads();
        *(bf16x8*)&Ah[sr * LDSW + sc] = va;
        *(bf16x8*)&Bh[sr * LDSW + sc] = vb;
        *(bf16x8*)&Al[sr * LDSW + sc] = va2;
        *(bf16x8*)&Bl[sr * LDSW + sc] = vb2;
        __syncthreads();
        bf16x8 ah[2], al[2], bh[2], bl[2];
#pragma unroll
        for (int mt = 0; mt < 2; ++mt) {
            ah[mt] = *(const bf16x8*)&Ah[(wm * 32 + mt * 16 + r16) * LDSW + q * 8];
            al[mt] = *(const bf16x8*)&Al[(wm * 32 + mt * 16 + r16) * LDSW + q * 8];
        }
#pragma unroll
        for (int nt = 0; nt < 2; ++nt) {
            bh[nt] = *(const bf16x8*)&Bh[(wn * 32 + nt * 16 + r16) * LDSW + q * 8];
            bl[nt] = *(const bf16x8*)&Bl[(wn * 32 + nt * 16 + r16) * LDSW + q * 8];
        }
#pragma unroll
        for (int mt = 0; mt < 2; ++mt)
#pragma unroll
            for (int nt = 0; nt < 2; ++nt) {
                acc[mt][nt] = __builtin_amdgcn_mfma_f32_16x16x32_bf16(ah[mt], bh[nt], acc[mt][nt], 0, 0, 0);
                acc[mt][nt] = __builtin_amdgcn_mfma_f32_16x16x32_bf16(ah[mt], bl[nt], acc[mt][nt], 0, 0, 0);
                acc[mt][nt] = __builtin_amdgcn_mfma_f32_16x16x32_bf16(al[mt], bh[nt], acc[mt][nt], 0, 0, 0);
            }
    }
#pragma unroll
    for (int mt = 0; mt < 2; ++mt)
#pragma unroll
        for (int nt = 0; nt < 2; ++nt)
#pragma unroll
            for (int i = 0; i < 4; ++i) {
                int row = m0 + wm * 32 + mt * 16 + q * 4 + i;
                int col = n0 + wn * 32 + nt * 16 + r16;
                C[(size_t)row * NN + col] = acc[mt][nt][i];
            }
}

// ---------------- spmm1: h1 = relu(A_sp @ support), float2 lanes, 2 rows/blk -
// emits h1 directly as split bf16 (hi + residual) for gemm23's MFMA
__global__ __launch_bounds__(256) void spmm_h1(const int* __restrict__ row_ptr,
                                               const int* __restrict__ csr_col,
                                               const float* __restrict__ csr_val,
                                               const float* __restrict__ in,
                                               __bf16* __restrict__ h1h,
                                               __bf16* __restrict__ h1l) {
    __shared__ int   s_col[2][128];
    __shared__ float s_val[2][128];
    __shared__ int   s_deg[2];
    const int tid = threadIdx.x;
    const int half = tid >> 7;
    const int d = tid & 127;            // float2 lane: dims 2d, 2d+1
    const int r = blockIdx.x * 2 + half;
    const int beg = row_ptr[r];
    const int deg = row_ptr[r + 1] - beg;
    if (d == 0) s_deg[half] = deg;
    __syncthreads();
    const int trips = (max(s_deg[0], s_deg[1]) + 127) >> 7;
    const float2* in2 = (const float2*)in;
    float ax = 0.f, ay = 0.f;
    for (int t = 0; t < trips; ++t) {
        int base = t * 128;
        __syncthreads();
        if (base + d < deg) {
            s_col[half][d] = csr_col[beg + base + d];
            s_val[half][d] = csr_val[beg + base + d];
        }
        __syncthreads();
        int m = deg - base; if (m > 128) m = 128; if (m < 0) m = 0;
        int e = 0;
        for (; e + 4 <= m; e += 4) {
            float2 x0 = in2[(size_t)s_col[half][e]     * 128 + d];
            float2 x1 = in2[(size_t)s_col[half][e + 1] * 128 + d];
            float2 x2 = in2[(size_t)s_col[half][e + 2] * 128 + d];
            float2 x3 = in2[(size_t)s_col[half][e + 3] * 128 + d];
            float v0 = s_val[half][e], v1 = s_val[half][e + 1];
            float v2 = s_val[half][e + 2], v3 = s_val[half][e + 3];
            ax += v0 * x0.x + v1 * x1.x + v2 * x2.x + v3 * x3.x;
            ay += v0 * x0.y + v1 * x1.y + v2 * x2.y + v3 * x3.y;
        }
        for (; e < m; ++e) {
            float2 xv = in2[(size_t)s_col[half][e] * 128 + d];
            float v = s_val[half][e];
            ax += v * xv.x;
            ay += v * xv.y;
        }
    }
    float rx = fmaxf(ax, 0.f), ry = fmaxf(ay, 0.f);
    __bf16 hx = (__bf16)rx, hy = (__bf16)ry;
    bf16x2 hv = {hx, hy};
    bf16x2 lv = {(__bf16)(rx - (float)hx), (__bf16)(ry - (float)hy)};
    *(bf16x2*)&h1h[(size_t)r * H1DIM + d * 2] = hv;
    *(bf16x2*)&h1l[(size_t)r * H1DIM + d * 2] = lv;
}

// ---------------- gemm23: [t2|t3] = h1 @ [W2|W3] via split-bf16 MFMA ---------
// BM=32, BN=128 (fused), BK=32, 4 waves side-by-side, wave tile 32x32
__global__ __launch_bounds__(256) void gemm23_mfma(const __bf16* __restrict__ ag_h,
                                                   const __bf16* __restrict__ ag_l,
                                                   const __bf16* __restrict__ bth,
                                                   const __bf16* __restrict__ btl,
                                                   float* __restrict__ t2,
                                                   float* __restrict__ t3) {
    constexpr int K = H1DIM, LDSW = 40;
    __shared__ __bf16 Ah[32 * LDSW], Al[32 * LDSW], Bh[128 * LDSW], Bl[128 * LDSW];
    const int tid = threadIdx.x;
    const int m0 = blockIdx.x * 32;
    const int lane = tid & 63, wn = tid >> 6;
    const int r16 = lane & 15, q = lane >> 4;
    const int ta = tid & 127;
    const int ar = ta >> 2, ac = (ta & 3) * 8;     // A stage: 32 rows x 4 chunks
    floatx4 acc[2][2] = {};

    for (int k0 = 0; k0 < K; k0 += 32) {
        const __bf16* asrc = (tid < 128) ? ag_h : ag_l;
        bf16x8 va = *(const bf16x8*)&asrc[(size_t)(m0 + ar) * K + k0 + ac];
        bf16x8 vbh[2], vbl[2];
#pragma unroll
        for (int v = 0; v < 2; ++v) {
            int id = tid + v * 256;
            int br = id >> 2, bc = (id & 3) * 8;
            vbh[v] = *(const bf16x8*)&bth[(size_t)br * K + k0 + bc];
            vbl[v] = *(const bf16x8*)&btl[(size_t)br * K + k0 + bc];
        }
        __syncthreads();
        {
            __bf16* adst = (tid < 128) ? Ah : Al;
            *(bf16x8*)&adst[ar * LDSW + ac] = va;
        }
#pragma unroll
        for (int v = 0; v < 2; ++v) {
            int id = tid + v * 256;
            int br = id >> 2, bc = (id & 3) * 8;
            *(bf16x8*)&Bh[br * LDSW + bc] = vbh[v];
            *(bf16x8*)&Bl[br * LDSW + bc] = vbl[v];
        }
        __syncthreads();
        bf16x8 ah[2], al[2], bh[2], bl[2];
#pragma unroll
        for (int mt = 0; mt < 2; ++mt) {
            ah[mt] = *(const bf16x8*)&Ah[(mt * 16 + r16) * LDSW + q * 8];
            al[mt] = *(const bf16x8*)&Al[(mt * 16 + r16) * LDSW + q * 8];
        }
#pragma unroll
        for (int nt = 0; nt < 2; ++nt) {
            bh[nt] = *(const bf16x8*)&Bh[(wn * 32 + nt * 16 + r16) * LDSW + q * 8];
            bl[nt] = *(const bf16x8*)&Bl[(wn * 32 + nt * 16 + r16) * LDSW + q * 8];
        }
#pragma unroll
        for (int mt = 0; mt < 2; ++mt)
#pragma unroll
            for (int nt = 0; nt < 2; ++nt) {
                acc[mt][nt] = __builtin_amdgcn_mfma_f32_16x16x32_bf16(ah[mt], bh[nt], acc[mt][nt], 0, 0, 0);
                acc[mt][nt] = __builtin_amdgcn_mfma_f32_16x16x32_bf16(ah[mt], bl[nt], acc[mt][nt], 0, 0, 0);
                acc[mt][nt] = __builtin_amdgcn_mfma_f32_16x16x32_bf16(al[mt], bh[nt], acc[mt][nt], 0, 0, 0);
            }
    }
#pragma unroll
    for (int mt = 0; mt < 2; ++mt)
#pragma unroll
        for (int nt = 0; nt < 2; ++nt)
#pragma unroll
            for (int i = 0; i < 4; ++i) {
                int row = m0 + mt * 16 + q * 4 + i;
                int col = wn * 32 + nt * 16 + r16;    // 0..127: <64 -> t2, else t3
                float vv = acc[mt][nt][i];
                if (col < 64) t2[(size_t)row * H2DIM + col] = vv;
                else          t3[(size_t)row * H2DIM + col - 64] = vv;
            }
}

// ---------------- spmm23: mu/z/logvar/zb, float2 lanes, 4 rows/block ---------
__global__ __launch_bounds__(256) void spmm_mu_logvar(const int* __restrict__ row_ptr,
                                                      const int* __restrict__ csr_col,
                                                      const float* __restrict__ csr_val,
                                                      const float* __restrict__ t2,
                                                      const float* __restrict__ t3,
                                                      float* __restrict__ mu,
                                                      float* __restrict__ z,
                                                      float* __restrict__ logvar,
                                                      __bf16* __restrict__ zb) {
    __shared__ int   s_col[4][64];
    __shared__ float s_val[4][64];
    __shared__ int   s_deg[4];
    const int tid = threadIdx.x;
    const int rl = tid >> 6;            // row within block (0..3)
    const int d = tid & 63;             // <32: t2 float2 lane, >=32: t3 float2 lane
    const int r = blockIdx.x * 4 + rl;
    const int beg = row_ptr[r];
    const int deg = row_ptr[r + 1] - beg;
    if (d == 0) s_deg[rl] = deg;
    __syncthreads();
    const int md = max(max(s_deg[0], s_deg[1]), max(s_deg[2], s_deg[3]));
    const int trips = (md + 63) >> 6;
    const float2* src2 = (const float2*)((d < 32) ? t2 : t3);
    const int dd = d & 31;
    float ax = 0.f, ay = 0.f;
    for (int t = 0; t < trips; ++t) {
        int base = t * 64;
        __syncthreads();
        if (base + d < deg) {
            s_col[rl][d] = csr_col[beg + base + d];
            s_val[rl][d] = csr_val[beg + base + d];
        }
        __syncthreads();
        int m = deg - base; if (m > 64) m = 64; if (m < 0) m = 0;
        int e = 0;
        for (; e + 4 <= m; e += 4) {
            float2 x0 = src2[(size_t)s_col[rl][e]     * 32 + dd];
            float2 x1 = src2[(size_t)s_col[rl][e + 1] * 32 + dd];
            float2 x2 = src2[(size_t)s_col[rl][e + 2] * 32 + dd];
            float2 x3 = src2[(size_t)s_col[rl][e + 3] * 32 + dd];
            float v0 = s_val[rl][e], v1 = s_val[rl][e + 1];
            float v2 = s_val[rl][e + 2], v3 = s_val[rl][e + 3];
            ax += v0 * x0.x + v1 * x1.x + v2 * x2.x + v3 * x3.x;
            ay += v0 * x0.y + v1 * x1.y + v2 * x2.y + v3 * x3.y;
        }
        for (; e < m; ++e) {
            float2 xv = src2[(size_t)s_col[rl][e] * 32 + dd];
            float v = s_val[rl][e];
            ax += v * xv.x;
            ay += v * xv.y;
        }
    }
    if (d < 32) {
        size_t o2 = (size_t)r * 32 + dd;
        float2 v = {ax, ay};
        ((float2*)mu)[o2] = v;
        ((float2*)z)[o2] = v;
        bf16x2 b = {(__bf16)ax, (__bf16)ay};
        *(bf16x2*)&zb[o2 * 2] = b;
    } else {
        size_t o2 = (size_t)r * 32 + dd;
        float2 v = {ax, ay};
        ((float2*)logvar)[o2] = v;
    }
}

// ---------------- adj_recon = z @ z^T via bf16 MFMA (unchanged, verified) ----
__global__ __launch_bounds__(256) void zzt_mfma(const __bf16* __restrict__ z,
                                                float* __restrict__ C) {
    const int tid = threadIdx.x;
    const int lane = tid & 63;
    const int wave = tid >> 6;
    const int wm = wave >> 1, wn = wave & 1;
    const int m0 = blockIdx.y * 128 + wm * 64;
    const int n0 = blockIdx.x * 128 + wn * 64;
    const int r16 = lane & 15;
    const int quad = lane >> 4;

    floatx4 acc[4][4] = {};
    const char* zb = (const char*)z;

#pragma unroll
    for (int h = 0; h < 2; ++h) {
        bf16x8 a[4], b[4];
#pragma unroll
        for (int mt = 0; mt < 4; ++mt)
            a[mt] = *(const bf16x8*)(zb + (m0 + mt * 16 + r16) * 128 + h * 64 + quad * 16);
#pragma unroll
        for (int nt = 0; nt < 4; ++nt)
            b[nt] = *(const bf16x8*)(zb + (n0 + nt * 16 + r16) * 128 + h * 64 + quad * 16);
#pragma unroll
        for (int mt = 0; mt < 4; ++mt)
#pragma unroll
            for (int nt = 0; nt < 4; ++nt)
                acc[mt][nt] = __builtin_amdgcn_mfma_f32_16x16x32_bf16(a[mt], b[nt], acc[mt][nt], 0, 0, 0);
    }

#pragma unroll
    for (int mt = 0; mt < 4; ++mt)
#pragma unroll
        for (int nt = 0; nt < 4; ++nt)
#pragma unroll
            for (int r = 0; r < 4; ++r) {
                int row = m0 + mt * 16 + quad * 4 + r;
                int col = n0 + nt * 16 + r16;
                C[(size_t)row * N_NODES + col] = acc[mt][nt][r];
            }
}

// ---------------- launch ----------------
extern "C" void kernel_launch(void* const* d_in, const int* in_sizes, int n_in,
                              void* d_out, int out_size, void* d_ws, size_t ws_size,
                              hipStream_t stream) {
    const float* x        = (const float*)d_in[0];
    const int*   adj_rows = (const int*)d_in[1];
    const int*   adj_cols = (const int*)d_in[2];
    const float* adj_vals = (const float*)d_in[3];
    const float* W1       = (const float*)d_in[4];
    const float* W2       = (const float*)d_in[5];
    const float* W3       = (const float*)d_in[6];
    const int E = in_sizes[1];
    const int n = N_NODES;

    char* ws = (char*)d_ws;
    size_t off = 0;
    auto alloc = [&](size_t bytes) {
        void* p = ws + off;
        off = (off + bytes + 255) & ~(size_t)255;
        return p;
    };
    int*    cnt     = (int*)alloc((size_t)n * 4);
    int*    row_ptr = (int*)alloc((size_t)(n + 1) * 4);
    int*    cursor  = (int*)alloc((size_t)n * 4);
    int*    csr_col = (int*)alloc((size_t)E * 4);
    float*  csr_val = (float*)alloc((size_t)E * 4);
    __bf16* xh      = (__bf16*)alloc((size_t)n * F_INDIM * 2);
    __bf16* xl      = (__bf16*)alloc((size_t)n * F_INDIM * 2);
    __bf16* w1th    = (__bf16*)alloc((size_t)H1DIM * F_INDIM * 2);
    __bf16* w1tl    = (__bf16*)alloc((size_t)H1DIM * F_INDIM * 2);
    __bf16* w23th   = (__bf16*)alloc((size_t)(2 * H2DIM) * H1DIM * 2);
    __bf16* w23tl   = (__bf16*)alloc((size_t)(2 * H2DIM) * H1DIM * 2);
    float*  support = (float*)alloc((size_t)n * H1DIM * 4);
    __bf16* h1h     = (__bf16*)alloc((size_t)n * H1DIM * 2);
    __bf16* h1l     = (__bf16*)alloc((size_t)n * H1DIM * 2);
    float*  t2      = (float*)alloc((size_t)n * H2DIM * 4);
    float*  t3      = (float*)alloc((size_t)n * H2DIM * 4);
    __bf16* zb      = (__bf16*)alloc((size_t)n * H2DIM * 2);

    float* out        = (float*)d_out;
    float* adj_recon  = out;
    float* z_out      = out + (size_t)n * n;
    float* mu_out     = z_out + (size_t)n * H2DIM;
    float* logvar_out = mu_out + (size_t)n * H2DIM;

    // CSR build
    hipMemsetAsync(cnt, 0, (size_t)n * 4, stream);
    count_rows<<<(E + 255) / 256, 256, 0, stream>>>(adj_rows, cnt, E);
    scan_rows<<<1, 1024, 0, stream>>>(cnt, row_ptr, cursor, n);
    scatter_edges<<<(E + 255) / 256, 256, 0, stream>>>(adj_rows, adj_cols, adj_vals,
                                                       cursor, csr_col, csr_val, E);

    // precision-preserving splits
    cast_split_x<<<(n * F_INDIM) / (256 * 4), 256, 0, stream>>>(x, xh, xl);
    transpose_cast_w<<<dim3(16, 8, 3), dim3(32, 8), 0, stream>>>(W1, W2, W3,
                                                                 w1th, w1tl, w23th, w23tl);

    // gc1
    gemm1_mfma<<<dim3(H1DIM / 64, n / 64), 256, 0, stream>>>(xh, xl, w1th, w1tl, support);
    spmm_h1<<<n / 2, 256, 0, stream>>>(row_ptr, csr_col, csr_val, support, h1h, h1l);

    // gc2 / gc3 fused
    gemm23_mfma<<<n / 32, 256, 0, stream>>>(h1h, h1l, w23th, w23tl, t2, t3);
    spmm_mu_logvar<<<n / 4, 256, 0, stream>>>(row_ptr, csr_col, csr_val, t2, t3,
                                              mu_out, z_out, logvar_out, zb);

    // decoder
    zzt_mfma<<<dim3(n / 128, n / 128), 256, 0, stream>>>(zb, adj_recon);
}